// Round 6
// baseline (172.939 us; speedup 1.0000x reference)
//
#include <hip/hip_runtime.h>

// Int8 fake-quant linear (exact integer accumulation):
//   sx = max|x|/128; qx = clamp(rint(x/sx),-128,127)
//   sw = max|w|/127; qw = clamp(rint(w/sw),-127,127)
//   out = mul * (sx*sw*(qx @ qw^T) + bias)
//
// qx/qw stored PERMUTED in workspace, in LDS chunk-plane order:
//   v4i index = ((blk*32 + kt)*4 + c)*256 + r
//   holds bytes [kt*64 + c*16 .. +15] of row blk*256+r.
// -> staging is a linear contiguous copy (global_load_lds, lane-linear dest)
// -> fragment reads are 32-lane-contiguous (verified: 0 bank conflicts)

typedef int v4i  __attribute__((ext_vector_type(4)));
typedef int v16i __attribute__((ext_vector_type(16)));

#define MDIM 4096
#define NDIM 8192
#define KDIM 2048
#define NT   (KDIM / 64)   // 32 K-tiles of BK=64 int8

typedef __attribute__((address_space(1))) void* gas_ptr;   // global
typedef __attribute__((address_space(3))) void* las_ptr;   // LDS

// ---------------- init: zero the two absmax slots ----------------
__global__ void init_scales(unsigned* s) {
    if (threadIdx.x < 2) s[threadIdx.x] = 0u;
}

// ---------------- fused absmax over x and w ----------------
#define XBLK 1024
__global__ void absmax2(const float4* __restrict__ x, int nx4,
                        const float4* __restrict__ w, int nw4,
                        unsigned* __restrict__ out) {
    const bool isx = blockIdx.x < XBLK;
    const float4* in = isx ? x : w;
    const int n4 = isx ? nx4 : nw4;
    const int nb = isx ? XBLK : (gridDim.x - XBLK);
    const int b  = isx ? blockIdx.x : (blockIdx.x - XBLK);
    float m = 0.0f;
    for (int i = b * blockDim.x + threadIdx.x; i < n4; i += nb * blockDim.x) {
        float4 v = in[i];
        m = fmaxf(m, fmaxf(fmaxf(fabsf(v.x), fabsf(v.y)),
                           fmaxf(fabsf(v.z), fabsf(v.w))));
    }
#pragma unroll
    for (int off = 32; off > 0; off >>= 1)
        m = fmaxf(m, __shfl_xor(m, off, 64));
    __shared__ float wm[4];
    if ((threadIdx.x & 63) == 0) wm[threadIdx.x >> 6] = m;
    __syncthreads();
    if (threadIdx.x == 0) {
        float mm = fmaxf(fmaxf(wm[0], wm[1]), fmaxf(wm[2], wm[3]));
        atomicMax(out + (isx ? 0 : 1), __float_as_uint(mm));
    }
}

// ---------------- fused quantize into PERMUTED int8 layout ----------------
// v4i idx: c = idx&3, r = (idx>>2)&255, kt = (idx>>10)&31, blk = idx>>15.
// Wave coalescing: 64 lanes = 16 rows x (4 chunks c) -> reads cover 16
// contiguous 256B segments; writes form 4 contiguous 256B clusters.
__global__ void quant2(const float4* __restrict__ x, v4i* __restrict__ qxp,
                       const float4* __restrict__ w, v4i* __restrict__ qwp,
                       const unsigned* __restrict__ scales) {
    const bool isx = blockIdx.x < XBLK;
    const float4* in = isx ? x : w;
    v4i* outp = isx ? qxp : qwp;
    const int total = isx ? (MDIM * KDIM / 16) : (NDIM * KDIM / 16);
    const int nb = isx ? XBLK : (gridDim.x - XBLK);
    const int b  = isx ? blockIdx.x : (blockIdx.x - XBLK);
    const float s  = __uint_as_float(scales[isx ? 0 : 1]) / (isx ? 128.0f : 127.0f);
    const float lo = isx ? -128.0f : -127.0f;
    for (int idx = b * blockDim.x + threadIdx.x; idx < total; idx += nb * blockDim.x) {
        const int c   = idx & 3;
        const int r   = (idx >> 2) & 255;
        const int kt  = (idx >> 10) & 31;
        const int blk = idx >> 15;
        const int row = blk * 256 + r;
        const float4* src = in + (size_t)row * (KDIM / 4) + kt * 16 + c * 4;
        int q[4];
#pragma unroll
        for (int j = 0; j < 4; ++j) {
            float4 v = src[j];
            int b0 = (int)fminf(fmaxf(rintf(v.x / s), lo), 127.0f);
            int b1 = (int)fminf(fmaxf(rintf(v.y / s), lo), 127.0f);
            int b2 = (int)fminf(fmaxf(rintf(v.z / s), lo), 127.0f);
            int b3 = (int)fminf(fmaxf(rintf(v.w / s), lo), 127.0f);
            q[j] = (b0 & 255) | ((b1 & 255) << 8) | ((b2 & 255) << 16) | (b3 << 24);
        }
        v4i qq; qq[0] = q[0]; qq[1] = q[1]; qq[2] = q[2]; qq[3] = q[3];
        outp[((size_t)(blk * 32 + kt) * 4 + c) * 256 + r] = qq;
    }
}

// ---------------- int8 MFMA GEMM, 256x256 tile, 4-deep ring ----------------
// 8 waves (2M x 4N); wave output 128x64 = 4x2 mfma_i32_32x32x32_i8.
// LDS per buffer: A,B each 4 chunk-planes x 256 rows x 16B (16 KB); 4 bufs = 128 KiB.
// SOFTWARE-PIPELINED phases (64 = 2 per K-tile): phase p issues the 6
// ds_read_b128 for phase p+1's fragments (register double-buffer f0/f1) and
// MFMAs fragments loaded in phase p-1 -> LDS pipe (576 cyc/phase) hides under
// the matrix pipe (586 cyc/phase). Compiler emits counted lgkmcnt(6).
// Counted vmcnt(6/4/0) at even-phase ends only; never drained early.
__global__ __launch_bounds__(512, 2) void gemm_i8(
    const signed char* __restrict__ qxp, const signed char* __restrict__ qwp,
    const float* __restrict__ bias, const float* __restrict__ mulv,
    const unsigned* __restrict__ scales, float* __restrict__ out) {
    __shared__ signed char ldsA[4][16384];
    __shared__ signed char ldsB[4][16384];

    const int t    = threadIdx.x;
    const int lane = t & 63;
    const int ln   = lane & 31;
    const int hi   = lane >> 5;
    const int w    = t >> 6;      // 0..7
    const int wr   = w >> 2;      // 0..1  (M half)
    const int wc   = w & 3;       // 0..3  (N quarter)

    // XCD-aware swizzle: 512 workgroups, 512 % 8 == 0 -> simple bijection.
    const int orig = blockIdx.x;
    const int wg   = ((orig & 7) << 6) | (orig >> 3);
    const int bm   = wg >> 5;     // 0..15
    const int bn   = wg & 31;     // 0..31

    // ---- staging: linear contiguous copy of 16KB tile slabs ----
    const signed char* srcA = qxp + (size_t)bm * (32 * 16384);
    const signed char* srcB = qwp + (size_t)bn * (32 * 16384);
    signed char* dA = &ldsA[0][0] + t * 16;   // wave-uniform base + lane*16
    signed char* dB = &ldsB[0][0] + t * 16;

    auto stageA = [&](int kt) {   // A-half of tile kt (2 loads)
        const signed char* sa = srcA + kt * 16384 + t * 16;
        const int buf = kt & 3;
        __builtin_amdgcn_global_load_lds((gas_ptr)sa,          (las_ptr)(dA + buf * 16384),        16, 0, 0);
        __builtin_amdgcn_global_load_lds((gas_ptr)(sa + 8192), (las_ptr)(dA + buf * 16384 + 8192), 16, 0, 0);
    };
    auto stageB = [&](int kt) {   // B-half of tile kt (2 loads)
        const signed char* sb = srcB + kt * 16384 + t * 16;
        const int buf = kt & 3;
        __builtin_amdgcn_global_load_lds((gas_ptr)sb,          (las_ptr)(dB + buf * 16384),        16, 0, 0);
        __builtin_amdgcn_global_load_lds((gas_ptr)(sb + 8192), (las_ptr)(dB + buf * 16384 + 8192), 16, 0, 0);
    };

    // ---- fragment offsets (chunk-plane: plane = 2*ks+hi, 32-lane contiguous) ----
    const int aOff = (wr * 128 + ln) * 16;   // + mt*512 + plane*4096
    const int bOff = (wc * 64  + ln) * 16;   // + nt*512 + plane*4096

#define LDFRAG(FA, FB, TILE, KS) do {                                        \
        const signed char* _A = &ldsA[(TILE) & 3][0] + (2*(KS)+hi) * 4096;   \
        const signed char* _B = &ldsB[(TILE) & 3][0] + (2*(KS)+hi) * 4096;   \
        FA[0] = *(const v4i*)(_A + aOff);                                    \
        FA[1] = *(const v4i*)(_A + aOff + 512);                              \
        FA[2] = *(const v4i*)(_A + aOff + 1024);                             \
        FA[3] = *(const v4i*)(_A + aOff + 1536);                             \
        FB[0] = *(const v4i*)(_B + bOff);                                    \
        FB[1] = *(const v4i*)(_B + bOff + 512);                              \
    } while (0)

#define MFMA8(FA, FB) do {                                                   \
        __builtin_amdgcn_s_setprio(1);                                       \
        acc[0][0] = __builtin_amdgcn_mfma_i32_32x32x32_i8(FA[0], FB[0], acc[0][0], 0, 0, 0); \
        acc[0][1] = __builtin_amdgcn_mfma_i32_32x32x32_i8(FA[0], FB[1], acc[0][1], 0, 0, 0); \
        acc[1][0] = __builtin_amdgcn_mfma_i32_32x32x32_i8(FA[1], FB[0], acc[1][0], 0, 0, 0); \
        acc[1][1] = __builtin_amdgcn_mfma_i32_32x32x32_i8(FA[1], FB[1], acc[1][1], 0, 0, 0); \
        acc[2][0] = __builtin_amdgcn_mfma_i32_32x32x32_i8(FA[2], FB[0], acc[2][0], 0, 0, 0); \
        acc[2][1] = __builtin_amdgcn_mfma_i32_32x32x32_i8(FA[2], FB[1], acc[2][1], 0, 0, 0); \
        acc[3][0] = __builtin_amdgcn_mfma_i32_32x32x32_i8(FA[3], FB[0], acc[3][0], 0, 0, 0); \
        acc[3][1] = __builtin_amdgcn_mfma_i32_32x32x32_i8(FA[3], FB[1], acc[3][1], 0, 0, 0); \
        __builtin_amdgcn_s_setprio(0);                                       \
    } while (0)

    v16i acc[4][2];
#pragma unroll
    for (int mt = 0; mt < 4; ++mt)
#pragma unroll
        for (int nt = 0; nt < 2; ++nt)
#pragma unroll
            for (int r = 0; r < 16; ++r) acc[mt][nt][r] = 0;

    v4i f0a[4], f0b[2];   // fragments for even phases (ks0)
    v4i f1a[4], f1b[2];   // fragments for odd phases (ks1)

    // ---- prologue: 3 tiles in flight; preload phase-0 fragments ----
    stageA(0); stageB(0);
    stageA(1); stageB(1);
    stageA(2); stageB(2);
    asm volatile("s_waitcnt vmcnt(8)" ::: "memory");   // tile 0 resident
    __builtin_amdgcn_s_barrier();
    LDFRAG(f0a, f0b, 0, 0);

    for (int kt = 0; kt < NT; ++kt) {
        // ---- even phase p=2kt: prefetch (tile kt, ks1); MFMA on f0 ----
        LDFRAG(f1a, f1b, kt, 1);
        if (kt + 3 < NT) stageA(kt + 3);
        __builtin_amdgcn_sched_barrier(0);
        __builtin_amdgcn_s_barrier();
        MFMA8(f0a, f0b);
        // counted wait: ensure tile kt+1 resident for next phase's prefetch
        if (kt <= NT - 4)      asm volatile("s_waitcnt vmcnt(6)" ::: "memory");
        else if (kt == NT - 3) asm volatile("s_waitcnt vmcnt(4)" ::: "memory");
        else if (kt == NT - 2) asm volatile("s_waitcnt vmcnt(0)" ::: "memory");
        __builtin_amdgcn_s_barrier();

        // ---- odd phase p=2kt+1: prefetch (tile kt+1, ks0); MFMA on f1 ----
        if (kt < NT - 1) LDFRAG(f0a, f0b, kt + 1, 0);
        if (kt + 3 < NT) stageB(kt + 3);
        __builtin_amdgcn_sched_barrier(0);
        __builtin_amdgcn_s_barrier();
        MFMA8(f1a, f1b);
        __builtin_amdgcn_s_barrier();
    }

    // ---- epilogue: out = fs*acc + mul*bias ----
    // C/D layout (32x32): col = lane&31, row = (r&3) + 8*(r>>2) + 4*(lane>>5)
    const float fm = mulv[0];
    const float fs = fm * (__uint_as_float(scales[0]) / 128.0f)
                        * (__uint_as_float(scales[1]) / 127.0f);
    const int colb = bn * 256 + wc * 64 + ln;
    const int hi4  = hi * 4;
#pragma unroll
    for (int nt = 0; nt < 2; ++nt) {
        const int ocol = colb + nt * 32;
        const float bv = bias[ocol] * fm;
#pragma unroll
        for (int mt = 0; mt < 4; ++mt) {
            float* op = out + (size_t)(bm * 256 + wr * 128 + mt * 32) * NDIM + ocol;
#pragma unroll
            for (int r = 0; r < 16; ++r) {
                const int row = (r & 3) + 8 * (r >> 2) + hi4;
                op[(size_t)row * NDIM] = fs * (float)acc[mt][nt][r] + bv;
            }
        }
    }
#undef LDFRAG
#undef MFMA8
}

extern "C" void kernel_launch(void* const* d_in, const int* in_sizes, int n_in,
                              void* d_out, int out_size, void* d_ws, size_t ws_size,
                              hipStream_t stream) {
    const float* x    = (const float*)d_in[0];
    const float* wgt  = (const float*)d_in[1];
    const float* bias = (const float*)d_in[2];
    const float* mulv = (const float*)d_in[3];
    float* out = (float*)d_out;

    unsigned* scales = (unsigned*)d_ws;
    signed char* qxp = (signed char*)d_ws + 256;
    signed char* qwp = qxp + (size_t)MDIM * KDIM;

    const int nx4 = MDIM * KDIM / 4;  // 2M float4
    const int nw4 = NDIM * KDIM / 4;  // 4M float4

    init_scales<<<1, 64, 0, stream>>>(scales);
    absmax2<<<3072, 256, 0, stream>>>((const float4*)x, nx4,
                                      (const float4*)wgt, nw4, scales);
    quant2<<<3072, 256, 0, stream>>>((const float4*)x, (v4i*)qxp,
                                     (const float4*)wgt, (v4i*)qwp, scales);

    gemm_i8<<<512, 512, 0, stream>>>(qxp, qwp, bias, mulv, scales, out);
}

// Round 7
// 153.295 us; speedup vs baseline: 1.1281x; 1.1281x over previous
//
#include <hip/hip_runtime.h>

// Int8 fake-quant linear (exact integer accumulation):
//   sx = max|x|/128; qx = clamp(rint(x/sx),-128,127)
//   sw = max|w|/127; qw = clamp(rint(w/sw),-127,127)
//   out = mul * (sx*sw*(qx @ qw^T) + bias)
//
// qx permuted in 128-row blocks:  v4i idx = ((blk*32+kt)*4 + c)*128 + r
// qw permuted in 256-row blocks:  v4i idx = ((blk*32+kt)*4 + c)*256 + r
// (chunk c = 16B of K; kt = 64-B K-tile). Staging is a linear contiguous
// copy (global_load_lds, lane-linear dest); fragment reads 32-lane
// contiguous (verified 0 bank conflicts R3/R5).

typedef int v4i  __attribute__((ext_vector_type(4)));
typedef int v16i __attribute__((ext_vector_type(16)));

#define MDIM 4096
#define NDIM 8192
#define KDIM 2048
#define NT   (KDIM / 64)   // 32 K-tiles of BK=64 int8

typedef __attribute__((address_space(1))) void* gas_ptr;   // global
typedef __attribute__((address_space(3))) void* las_ptr;   // LDS

// ---------------- init: zero the two absmax slots ----------------
__global__ void init_scales(unsigned* s) {
    if (threadIdx.x < 2) s[threadIdx.x] = 0u;
}

// ---------------- fused absmax over x and w ----------------
#define XBLK 1024
__global__ void absmax2(const float4* __restrict__ x, int nx4,
                        const float4* __restrict__ w, int nw4,
                        unsigned* __restrict__ out) {
    const bool isx = blockIdx.x < XBLK;
    const float4* in = isx ? x : w;
    const int n4 = isx ? nx4 : nw4;
    const int nb = isx ? XBLK : (gridDim.x - XBLK);
    const int b  = isx ? blockIdx.x : (blockIdx.x - XBLK);
    float m = 0.0f;
    for (int i = b * blockDim.x + threadIdx.x; i < n4; i += nb * blockDim.x) {
        float4 v = in[i];
        m = fmaxf(m, fmaxf(fmaxf(fabsf(v.x), fabsf(v.y)),
                           fmaxf(fabsf(v.z), fabsf(v.w))));
    }
#pragma unroll
    for (int off = 32; off > 0; off >>= 1)
        m = fmaxf(m, __shfl_xor(m, off, 64));
    __shared__ float wm[4];
    if ((threadIdx.x & 63) == 0) wm[threadIdx.x >> 6] = m;
    __syncthreads();
    if (threadIdx.x == 0) {
        float mm = fmaxf(fmaxf(wm[0], wm[1]), fmaxf(wm[2], wm[3]));
        atomicMax(out + (isx ? 0 : 1), __float_as_uint(mm));
    }
}

// ---------------- fused quantize into PERMUTED int8 layouts ----------------
// x: 128-row blocks;  w: 256-row blocks. Reads cover contiguous 64B row
// segments; writes form contiguous 256B clusters per same-c lane group.
__global__ void quant2(const float4* __restrict__ x, v4i* __restrict__ qxp,
                       const float4* __restrict__ w, v4i* __restrict__ qwp,
                       const unsigned* __restrict__ scales) {
    const bool isx = blockIdx.x < XBLK;
    const float4* in = isx ? x : w;
    v4i* outp = isx ? qxp : qwp;
    const int total = isx ? (MDIM * KDIM / 16) : (NDIM * KDIM / 16);
    const int nb = isx ? XBLK : (gridDim.x - XBLK);
    const int b  = isx ? blockIdx.x : (blockIdx.x - XBLK);
    const float s  = __uint_as_float(scales[isx ? 0 : 1]) / (isx ? 128.0f : 127.0f);
    const float lo = isx ? -128.0f : -127.0f;
    for (int idx = b * blockDim.x + threadIdx.x; idx < total; idx += nb * blockDim.x) {
        int c, r, kt, blk, row, oidx;
        if (isx) {   // 128-row blocks
            c   = idx & 3;
            r   = (idx >> 2) & 127;
            kt  = (idx >> 9) & 31;
            blk = idx >> 14;
            row = blk * 128 + r;
            oidx = ((blk * 32 + kt) * 4 + c) * 128 + r;
        } else {     // 256-row blocks
            c   = idx & 3;
            r   = (idx >> 2) & 255;
            kt  = (idx >> 10) & 31;
            blk = idx >> 15;
            row = blk * 256 + r;
            oidx = ((blk * 32 + kt) * 4 + c) * 256 + r;
        }
        const float4* src = in + (size_t)row * (KDIM / 4) + kt * 16 + c * 4;
        int q[4];
#pragma unroll
        for (int j = 0; j < 4; ++j) {
            float4 v = src[j];
            int b0 = (int)fminf(fmaxf(rintf(v.x / s), lo), 127.0f);
            int b1 = (int)fminf(fmaxf(rintf(v.y / s), lo), 127.0f);
            int b2 = (int)fminf(fmaxf(rintf(v.z / s), lo), 127.0f);
            int b3 = (int)fminf(fmaxf(rintf(v.w / s), lo), 127.0f);
            q[j] = (b0 & 255) | ((b1 & 255) << 8) | ((b2 & 255) << 16) | (b3 << 24);
        }
        v4i qq; qq[0] = q[0]; qq[1] = q[1]; qq[2] = q[2]; qq[3] = q[3];
        outp[oidx] = qq;
    }
}

// ---------------- int8 MFMA GEMM, 128x256 tile, ring-3, 2 blocks/CU --------
// 256 threads = 4 waves (1M x 4N); each wave owns 128x64 = 4x2 of
// mfma_i32_32x32x32_i8 (128 acc regs). LDS per buffer: A 4 planes x 128 rows
// x 16B (8 KB) + B 4 planes x 256 rows x 16B (16 KB); ring 3 = 72 KiB ->
// TWO blocks per CU; their phases interleave (LDS drain of one hides under
// MFMA of the other -- the m114 mechanism).
// Per K-tile (R5-proven shape): {12 ds_read_b128; stage tile kt+2 (6
// global_load_lds); s_barrier; setprio(1); 16 MFMA; setprio(0);
// vmcnt(6); s_barrier}. Ring-3 stage-2-ahead is race-free: stage(kt+2)
// overwrites buf (kt-1)%3 whose reads drained before the previous barrier.
__global__ __launch_bounds__(256, 2) void gemm_i8(
    const signed char* __restrict__ qxp, const signed char* __restrict__ qwp,
    const float* __restrict__ bias, const float* __restrict__ mulv,
    const unsigned* __restrict__ scales, float* __restrict__ out) {
    __shared__ signed char ldsA[3][8192];
    __shared__ signed char ldsB[3][16384];

    const int t    = threadIdx.x;   // 0..255
    const int lane = t & 63;
    const int ln   = lane & 31;
    const int hi   = lane >> 5;
    const int wc   = t >> 6;        // 0..3 (N quarter)

    // XCD-aware swizzle: 1024 workgroups, 1024 % 8 == 0 -> bijection.
    const int orig = blockIdx.x;
    const int wg   = ((orig & 7) << 7) | (orig >> 3);
    const int bm   = wg >> 5;       // 0..31 (128-row panel)
    const int bn   = wg & 31;       // 0..31 (256-col panel)

    const signed char* srcA = qxp + (size_t)bm * (32 * 8192);
    const signed char* srcB = qwp + (size_t)bn * (32 * 16384);
    signed char* dA0 = &ldsA[0][0] + t * 16;   // wave-uniform base + lane*16
    signed char* dB0 = &ldsB[0][0] + t * 16;

    auto stage = [&](int kt, int buf) {
        const signed char* sa = srcA + kt * 8192  + t * 16;
        const signed char* sb = srcB + kt * 16384 + t * 16;
        signed char* da = dA0 + buf * 8192;
        signed char* db = dB0 + buf * 16384;
        __builtin_amdgcn_global_load_lds((gas_ptr)sa,           (las_ptr)da,            16, 0, 0);
        __builtin_amdgcn_global_load_lds((gas_ptr)(sa + 4096),  (las_ptr)(da + 4096),   16, 0, 0);
        __builtin_amdgcn_global_load_lds((gas_ptr)sb,           (las_ptr)db,            16, 0, 0);
        __builtin_amdgcn_global_load_lds((gas_ptr)(sb + 4096),  (las_ptr)(db + 4096),   16, 0, 0);
        __builtin_amdgcn_global_load_lds((gas_ptr)(sb + 8192),  (las_ptr)(db + 8192),   16, 0, 0);
        __builtin_amdgcn_global_load_lds((gas_ptr)(sb + 12288), (las_ptr)(db + 12288),  16, 0, 0);
    };

    // fragment offsets: A plane stride 2048 (128 rows), B plane stride 4096.
    const int aOff = ln * 16;                  // + mt*512 + plane*2048
    const int bOff = (wc * 64 + ln) * 16;      // + nt*512 + plane*4096

    v16i acc[4][2];
#pragma unroll
    for (int mt = 0; mt < 4; ++mt)
#pragma unroll
        for (int nt = 0; nt < 2; ++nt)
#pragma unroll
            for (int r = 0; r < 16; ++r) acc[mt][nt][r] = 0;

    // ---- prologue: 2 tiles in flight; tile 0 resident before loop ----
    stage(0, 0);
    stage(1, 1);
    asm volatile("s_waitcnt vmcnt(6)" ::: "memory");   // tile 0 done
    __builtin_amdgcn_s_barrier();

    int cur = 0, stg = 2;
    for (int kt = 0; kt < NT; ++kt) {
        const signed char* Ab = &ldsA[cur][0];
        const signed char* Bb = &ldsB[cur][0];

        v4i a0[4], a1[4], b0[2], b1[2];
#pragma unroll
        for (int mt = 0; mt < 4; ++mt) a0[mt] = *(const v4i*)(Ab + hi * 2048 + aOff + mt * 512);
#pragma unroll
        for (int nt = 0; nt < 2; ++nt) b0[nt] = *(const v4i*)(Bb + hi * 4096 + bOff + nt * 512);
#pragma unroll
        for (int mt = 0; mt < 4; ++mt) a1[mt] = *(const v4i*)(Ab + (2 + hi) * 2048 + aOff + mt * 512);
#pragma unroll
        for (int nt = 0; nt < 2; ++nt) b1[nt] = *(const v4i*)(Bb + (2 + hi) * 4096 + bOff + nt * 512);

        if (kt + 2 < NT) stage(kt + 2, stg);
        __builtin_amdgcn_s_barrier();

        __builtin_amdgcn_s_setprio(1);
#pragma unroll
        for (int mt = 0; mt < 4; ++mt)
#pragma unroll
            for (int nt = 0; nt < 2; ++nt)
                acc[mt][nt] = __builtin_amdgcn_mfma_i32_32x32x32_i8(
                    a0[mt], b0[nt], acc[mt][nt], 0, 0, 0);
#pragma unroll
        for (int mt = 0; mt < 4; ++mt)
#pragma unroll
            for (int nt = 0; nt < 2; ++nt)
                acc[mt][nt] = __builtin_amdgcn_mfma_i32_32x32x32_i8(
                    a1[mt], b1[nt], acc[mt][nt], 0, 0, 0);
        __builtin_amdgcn_s_setprio(0);

        if (kt < NT - 1) {
            if (kt < NT - 2) asm volatile("s_waitcnt vmcnt(6)" ::: "memory");
            else             asm volatile("s_waitcnt vmcnt(0)" ::: "memory");
            __builtin_amdgcn_s_barrier();
        }
        cur = (cur == 2) ? 0 : cur + 1;
        stg = (stg == 2) ? 0 : stg + 1;
    }

    // ---- epilogue: out = fs*acc + mul*bias ----
    // C/D layout (32x32): col = lane&31, row = (r&3) + 8*(r>>2) + 4*(lane>>5)
    const float fm = mulv[0];
    const float fs = fm * (__uint_as_float(scales[0]) / 128.0f)
                        * (__uint_as_float(scales[1]) / 127.0f);
    const int colb = bn * 256 + wc * 64 + ln;
    const int hi4  = hi * 4;
#pragma unroll
    for (int nt = 0; nt < 2; ++nt) {
        const int ocol = colb + nt * 32;
        const float bv = bias[ocol] * fm;
#pragma unroll
        for (int mt = 0; mt < 4; ++mt) {
            float* op = out + (size_t)(bm * 128 + mt * 32) * NDIM + ocol;
#pragma unroll
            for (int r = 0; r < 16; ++r) {
                const int row = (r & 3) + 8 * (r >> 2) + hi4;
                op[(size_t)row * NDIM] = fs * (float)acc[mt][nt][r] + bv;
            }
        }
    }
}

extern "C" void kernel_launch(void* const* d_in, const int* in_sizes, int n_in,
                              void* d_out, int out_size, void* d_ws, size_t ws_size,
                              hipStream_t stream) {
    const float* x    = (const float*)d_in[0];
    const float* wgt  = (const float*)d_in[1];
    const float* bias = (const float*)d_in[2];
    const float* mulv = (const float*)d_in[3];
    float* out = (float*)d_out;

    unsigned* scales = (unsigned*)d_ws;
    signed char* qxp = (signed char*)d_ws + 256;
    signed char* qwp = qxp + (size_t)MDIM * KDIM;

    const int nx4 = MDIM * KDIM / 4;  // 2M float4
    const int nw4 = NDIM * KDIM / 4;  // 4M float4

    init_scales<<<1, 64, 0, stream>>>(scales);
    absmax2<<<3072, 256, 0, stream>>>((const float4*)x, nx4,
                                      (const float4*)wgt, nw4, scales);
    quant2<<<3072, 256, 0, stream>>>((const float4*)x, (v4i*)qxp,
                                     (const float4*)wgt, (v4i*)qwp, scales);

    gemm_i8<<<1024, 256, 0, stream>>>(qxp, qwp, bias, mulv, scales, out);
}